// Round 13
// baseline (86.058 us; speedup 1.0000x reference)
//
#include <hip/hip_runtime.h>

#define DEVINL __device__ __forceinline__

typedef float f32x2 __attribute__((ext_vector_type(2)));

// ---------------------------------------------------------------------------
// Compile-time circuit constants via GF(2) linear-map tracking.
// Round-13: 6 lane bits / 4 reg bits, TWO SAMPLES PER THREAD.
// R12 counters: qsim 41us, VALUBusy 42%, LDS 22%, no spill -> 58% idle from
// one serial dependency chain/wave (10 serial gates, serial WHT/reduce).
// Two samples per thread = two independent chains in every latency-critical
// phase; same wave-level instruction count (2 samples/wave unchanged).
// 6-bit lane basis change (R8-verified machinery) maps the gate lane-mask
// chain {1,3,6,12,24,48(w0,w9 doubled)} -> {32,16,7,8,2,1}:
//   w0/w9->DPP1, w1->DPP2, w2->DPP8(ror8), w3->DPP7(half_mirror),
//   w4->swz16, w5->bperm32 (only bpermute), w6/7/8 reg-local.
// Phase folding = R4/R5-verified 6/4 scheme (reg rows {15,0,0,0,0,0,8,12,
// 14,15}): w1..w5 phases -> lane factor; w6/w7 -> P/Q into t23; w8+(w0*w9)
// -> G0/G1 per-amp.  All masks/rows constexpr + static_asserted; all state
// indices closed-form static (rule #20).
// ---------------------------------------------------------------------------
struct GC { int laneXor, regXor, rowL, rowR; };
struct Circ { GC g[20]; int sgnL[10], sgnR[10]; int lsel[6]; };

constexpr Circ build_circ() {
    Circ c{};
    unsigned A[10] = {};
    for (int i = 0; i < 10; ++i) A[i] = 1u << i;
    for (int w = 0; w < 10; ++w) {
        int pos = 9 - w;
        unsigned m = 1u << pos;
        c.g[w] = GC{ int(m >> 4), int(m & 15u), int(m >> 4), int(m & 15u) };
    }
    // layer 0 CNOT ring, range r=1
    for (int q = 0; q < 10; ++q) { int pc = 9 - q, pt = 9 - ((q + 1) % 10); A[pt] ^= A[pc]; }
    // invert A over GF(2)
    unsigned M[10] = {}, Inv[10] = {};
    for (int i = 0; i < 10; ++i) { M[i] = A[i]; Inv[i] = 1u << i; }
    for (int col = 0; col < 10; ++col) {
        int piv = col;
        while (!((M[piv] >> col) & 1u)) ++piv;
        unsigned tm = M[col]; M[col] = M[piv]; M[piv] = tm;
        unsigned ti = Inv[col]; Inv[col] = Inv[piv]; Inv[piv] = ti;
        for (int r = 0; r < 10; ++r)
            if (r != col && ((M[r] >> col) & 1u)) { M[r] ^= M[col]; Inv[r] ^= Inv[col]; }
    }
    // layer 1 Rot gates (6/4 split): m = A^{-1} e_pos, row = A[pos]
    for (int w = 0; w < 10; ++w) {
        int pos = 9 - w;
        unsigned m = 0;
        for (int i = 0; i < 10; ++i) m |= ((Inv[i] >> pos) & 1u) << i;
        unsigned row = A[pos];
        c.g[10 + w] = GC{ int(m >> 4), int(m & 15u), int(row >> 4), int(row & 15u) };
    }
    // layer 1 CNOT ring, range r=2
    for (int q = 0; q < 10; ++q) { int pc = 9 - q, pt = 9 - ((q + 2) % 10); A[pt] ^= A[pc]; }
    for (int q = 0; q < 10; ++q) { unsigned row = A[9 - q]; c.sgnL[q] = int(row >> 4); c.sgnR[q] = int(row & 15u); }

    // ---- basis change on the 6 lane bits -------------------------------
    // chain v1={b0}(w5), v2={b0,b1}(w4), v3={b1,b2}(w3), v4={b2,b3}(w2),
    // v5={b3,b4}(w1), v6={b4,b5}(w0 AND w9, doubled).
    // targets: v1->32(bperm), v2->16(swz), v3->7(DPP), v4->8(DPP),
    //          v5->2(DPP), v6->1(DPP, doubled gets cheapest).
    unsigned Ucols[6] = {};
    {
        unsigned tgt[6] = {32, 16, 7, 8, 2, 1};
        unsigned acc = 0;
        for (int k = 0; k < 6; ++k) { acc ^= tgt[k]; Ucols[k] = acc; }
    }
    unsigned Urows[6] = {};
    for (int r = 0; r < 6; ++r)
        for (int cc = 0; cc < 6; ++cc)
            Urows[r] |= ((Ucols[cc] >> r) & 1u) << cc;
    unsigned MM[6] = {}, AI[6] = {};
    for (int i = 0; i < 6; ++i) { MM[i] = Urows[i]; AI[i] = 1u << i; }
    for (int col = 0; col < 6; ++col) {
        int piv = col;
        while (!((MM[piv] >> col) & 1u)) ++piv;
        unsigned tm = MM[col]; MM[col] = MM[piv]; MM[piv] = tm;
        unsigned ti = AI[col]; AI[col] = AI[piv]; AI[piv] = ti;
        for (int r = 0; r < 6; ++r)
            if (r != col && ((MM[r] >> col) & 1u)) { MM[r] ^= MM[col]; AI[r] ^= AI[col]; }
    }
    for (int w = 0; w < 10; ++w) {
        unsigned mL = unsigned(c.g[10 + w].laneXor);
        unsigned nm = 0;
        for (int i = 0; i < 6; ++i) if ((mL >> i) & 1u) nm ^= Ucols[i];
        c.g[10 + w].laneXor = int(nm);
        unsigned rL = unsigned(c.g[10 + w].rowL);
        unsigned nr = 0;
        for (int i = 0; i < 6; ++i) if ((rL >> i) & 1u) nr ^= AI[i];
        c.g[10 + w].rowL = int(nr);
    }
    for (int q = 0; q < 10; ++q) {
        unsigned sL = unsigned(c.sgnL[q]);
        unsigned ns = 0;
        for (int i = 0; i < 6; ++i) if ((sL >> i) & 1u) ns ^= AI[i];
        c.sgnL[q] = int(ns);
    }
    // wire w (0..5) sits at position 9-w = 4+(5-w): lane bit jj=5-w -> row jj
    for (int o = 0; o < 6; ++o) c.lsel[o] = int(AI[o]);
    return c;
}

constexpr Circ CC = build_circ();

// Final gate inventory (computed, then asserted).
static_assert(CC.g[10].laneXor == 1  && CC.g[10].regXor == 0,  "w0");
static_assert(CC.g[11].laneXor == 2  && CC.g[11].regXor == 0,  "w1");
static_assert(CC.g[12].laneXor == 8  && CC.g[12].regXor == 0,  "w2");
static_assert(CC.g[13].laneXor == 7  && CC.g[13].regXor == 0,  "w3");
static_assert(CC.g[14].laneXor == 16 && CC.g[14].regXor == 0,  "w4");
static_assert(CC.g[15].laneXor == 32 && CC.g[15].regXor == 8,  "w5");
static_assert(CC.g[16].laneXor == 0  && CC.g[16].regXor == 12, "w6");
static_assert(CC.g[17].laneXor == 0  && CC.g[17].regXor == 6,  "w7");
static_assert(CC.g[18].laneXor == 0  && CC.g[18].regXor == 3,  "w8");
static_assert(CC.g[19].laneXor == 1  && CC.g[19].regXor == 1,  "w9");
// Phase folding relies on these reg rows (basis change doesn't touch them).
static_assert(CC.g[10].rowR == 15, "w0 rowR");
static_assert(CC.g[11].rowR == 0,  "w1 rowR");
static_assert(CC.g[12].rowR == 0,  "w2 rowR");
static_assert(CC.g[13].rowR == 0,  "w3 rowR");
static_assert(CC.g[14].rowR == 0,  "w4 rowR");
static_assert(CC.g[15].rowR == 0,  "w5 rowR");
static_assert(CC.g[16].rowR == 8,  "w6 rowR");
static_assert(CC.g[17].rowR == 12, "w7 rowR");
static_assert(CC.g[18].rowR == 14, "w8 rowR");
static_assert(CC.g[19].rowR == 15, "w9 rowR");

#if __has_builtin(__builtin_amdgcn_permlane32_swap)
#define HAS_PL32 1
#else
#define HAS_PL32 0
#endif
#if __has_builtin(__builtin_amdgcn_permlane16_swap)
#define HAS_PL16 1
#else
#define HAS_PL16 0
#endif

DEVINL float csw(float v, int sw) {
    return __int_as_float(__float_as_int(v) ^ sw);
}
DEVINL int sgnw(int lane, int rowL) {
    return (__popc(unsigned(lane & rowL)) & 1) << 31;
}

// lane-xor fetch: 1,2,3 DPP quad; 7 DPP half_mirror; 8 DPP ror8 (all proven
// R7/R8/R12); 16 ds_swizzle; 32 ds_bpermute (full 64 lanes).
template<int XOR>
DEVINL float fetch(float v, int lane) {
    if constexpr (XOR == 0)      return v;
    else if constexpr (XOR == 1) return __int_as_float(__builtin_amdgcn_update_dpp(0, __float_as_int(v), 0xB1, 0xF, 0xF, true));
    else if constexpr (XOR == 2) return __int_as_float(__builtin_amdgcn_update_dpp(0, __float_as_int(v), 0x4E, 0xF, 0xF, true));
    else if constexpr (XOR == 3) return __int_as_float(__builtin_amdgcn_update_dpp(0, __float_as_int(v), 0x1B, 0xF, 0xF, true));
    else if constexpr (XOR == 7) return __int_as_float(__builtin_amdgcn_update_dpp(0, __float_as_int(v), 0x141, 0xF, 0xF, true));
    else if constexpr (XOR == 8) return __int_as_float(__builtin_amdgcn_update_dpp(0, __float_as_int(v), 0x128, 0xF, 0xF, true));
    else if constexpr (XOR < 32) return __int_as_float(__builtin_amdgcn_ds_swizzle(__float_as_int(v), 0x1F | (XOR << 10)));
    else                         return __int_as_float(__builtin_amdgcn_ds_bpermute((lane ^ XOR) << 2, __float_as_int(v)));
}

// butterfly pair-sums for the reduce (exact, convention-independent)
DEVINL float bsum16(float v, int lane) {
#if HAS_PL16
    auto r = __builtin_amdgcn_permlane16_swap(__float_as_int(v), __float_as_int(v), false, false);
    return __int_as_float(r[0]) + __int_as_float(r[1]);
#else
    return v + fetch<16>(v, lane);
#endif
}
DEVINL float bsum32(float v, int lane) {
#if HAS_PL32
    auto r = __builtin_amdgcn_permlane32_swap(__float_as_int(v), __float_as_int(v), false, false);
    return __int_as_float(r[0]) + __int_as_float(r[1]);
#else
    return v + fetch<32>(v, lane);
#endif
}

DEVINL void pk_fma_acc(f32x2& a, f32x2 t, f32x2 b) {
    asm("v_pk_fma_f32 %0, %1, %2, %0" : "+v"(a) : "v"(t), "v"(b));
}

DEVINL f32x2 cmul(f32x2 a, f32x2 b) {
    f32x2 r;
    r.x = a.x * b.x - a.y * b.y;
    r.y = a.x * b.y + a.y * b.x;
    return r;
}

// ---------------------------------------------------------------------------
// Constants (qprep): [0..39] layer-0 Rot mats; [40..49] tan(th/2);
// [50..69] (cos(phi/2), -sin(phi/2)); [70] prod cos(th/2)
// ---------------------------------------------------------------------------
__device__ __attribute__((aligned(16))) float g_cst[80];

__global__ void qprep(const float* __restrict__ qw) {
    int g = threadIdx.x;
    if (g < 10) {
        float phi = qw[g * 3 + 0], th = qw[g * 3 + 1], om = qw[g * 3 + 2];
        float c = cosf(0.5f * th), s = sinf(0.5f * th);
        float apo = 0.5f * (phi + om), amo = 0.5f * (phi - om);
        g_cst[g * 4 + 0] =  cosf(apo) * c;
        g_cst[g * 4 + 1] = -sinf(apo) * c;
        g_cst[g * 4 + 2] = -cosf(amo) * s;
        g_cst[g * 4 + 3] = -sinf(amo) * s;
    } else if (g < 20) {
        int w = g - 10;
        float phi = qw[g * 3 + 0], th = qw[g * 3 + 1];
        float c = cosf(0.5f * th), s = sinf(0.5f * th);
        g_cst[40 + w] = s / c;
        g_cst[50 + w * 2 + 0] =  cosf(0.5f * phi);
        g_cst[50 + w * 2 + 1] = -sinf(0.5f * phi);
    } else if (g == 20) {
        float p = 1.f;
        for (int w = 0; w < 10; ++w) p *= cosf(0.5f * qw[(10 + w) * 3 + 1]);
        g_cst[70] = p;
    }
}

DEVINL f32x2 mkE(const float* cst, int w, int lane) {
    f32x2 E;
    E.x = cst[50 + w * 2];
    E.y = csw(cst[50 + w * 2 + 1], sgnw(lane, CC.g[10 + w].rowL));
    return E;
}

// per-wire embedding factor: |0> --RY(x)--> --Rot(layer0)--> (f0, f1)
DEVINL void wf(const float* cst, float xw, int w, f32x2& f0, f32x2& f1) {
    float h = 0.5f * xw;
    float s = __sinf(h), c = __cosf(h);
    float m0 = cst[w * 4 + 0], m1 = cst[w * 4 + 1], m2 = cst[w * 4 + 2], m3 = cst[w * 4 + 3];
    f0.x =  m0 * c + m2 * s;
    f0.y =  m1 * c + m3 * s;
    f1.x = -m2 * c + m0 * s;
    f1.y =  m3 * c - m1 * s;
}

// Build one sample's 16 amplitudes (R4/R5-verified 6/4 folding).
DEVINL void build_state(const float* cst, const float* xb, int lane, f32x2 (&a2)[16]) {
    // reg-wire tables: bit0=w9, bit1=w8, bit2=w7, bit3=w6
    f32x2 t01[4], t23[4];
    {
        f32x2 a0, a1, b0, b1;
        wf(cst, xb[9], 9, a0, a1);
        wf(cst, xb[8], 8, b0, b1);
        t01[0] = cmul(a0, b0); t01[1] = cmul(a1, b0);
        t01[2] = cmul(a0, b1); t01[3] = cmul(a1, b1);
        wf(cst, xb[7], 7, a0, a1);
        wf(cst, xb[6], 6, b0, b1);
        t23[0] = cmul(a0, b0); t23[1] = cmul(a1, b0);
        t23[2] = cmul(a0, b1); t23[3] = cmul(a1, b1);
    }
    // lane factor: E_A (w1..w5) * cos-product * 6 lane-wire factors
    f32x2 lf;
    {
        f32x2 ea = mkE(cst, 1, lane);
        ea = cmul(ea, mkE(cst, 2, lane));
        ea = cmul(ea, mkE(cst, 3, lane));
        ea = cmul(ea, mkE(cst, 4, lane));
        ea = cmul(ea, mkE(cst, 5, lane));
        float sc = cst[70];
        lf.x = ea.x * sc; lf.y = ea.y * sc;
        #pragma unroll
        for (int jj = 0; jj < 6; ++jj) {
            int w = 5 - jj;                 // lane bit jj <-> wire 5-jj
            f32x2 f0, f1;
            wf(cst, xb[w], w, f0, f1);
            int bit = __popc(unsigned(lane & CC.lsel[jj])) & 1;
            f32x2 p; p.x = bit ? f1.x : f0.x; p.y = bit ? f1.y : f0.y;
            lf = cmul(lf, p);
        }
    }
    // w6/w7 phases -> t23: C(0)=P, C(1)=Q, C(2)=conj(P), C(3)=conj(Q)
    f32x2 E6 = mkE(cst, 6, lane), E7 = mkE(cst, 7, lane);
    float Pr_ = E6.x * E7.x - E6.y * E7.y, Pi_ = E6.x * E7.y + E6.y * E7.x;
    float Qr_ = E6.x * E7.x + E6.y * E7.y, Qi_ = E6.y * E7.x - E6.x * E7.y;
    f32x2 t23p[4];
    t23p[0].x = t23[0].x * Pr_ - t23[0].y * Pi_;  t23p[0].y = t23[0].x * Pi_ + t23[0].y * Pr_;
    t23p[1].x = t23[1].x * Qr_ - t23[1].y * Qi_;  t23p[1].y = t23[1].x * Qi_ + t23[1].y * Qr_;
    t23p[2].x = t23[2].x * Pr_ + t23[2].y * Pi_;  t23p[2].y = t23[2].y * Pr_ - t23[2].x * Pi_;
    t23p[3].x = t23[3].x * Qr_ + t23[3].y * Qi_;  t23p[3].y = t23[3].y * Qr_ - t23[3].x * Qi_;
    // w8 + (w0*w9) phases: G0 = E8*EB, G1 = E8*conj(EB), EB = E0*E9
    f32x2 E0 = mkE(cst, 0, lane), E9 = mkE(cst, 9, lane), E8 = mkE(cst, 8, lane);
    f32x2 EB = cmul(E0, E9);
    f32x2 G0 = cmul(E8, EB);
    f32x2 EBc; EBc.x = EB.x; EBc.y = -EB.y;
    f32x2 G1 = cmul(E8, EBc);
    // g4H[v][conj] = lf * t01[v] * (G(v&1) or conj)
    f32x2 g4H[4][2];
    #pragma unroll
    for (int v = 0; v < 4; ++v) {
        f32x2 g = cmul(lf, t01[v]);
        f32x2 G = (v & 1) ? G1 : G0;
        g4H[v][0] = cmul(g, G);
        f32x2 Gc; Gc.x = G.x; Gc.y = -G.y;
        g4H[v][1] = cmul(g, Gc);
    }
    // amps: conj flag = parity(r&14) = (v>>1) ^ parity(j)
    #pragma unroll
    for (int r = 0; r < 16; ++r) {
        const int v = r & 3, j = r >> 2;
        const int sel = ((v >> 1) ^ j ^ (j >> 1)) & 1;
        a2[r] = cmul(g4H[v][sel], t23p[j]);
    }
}

// Layer-1 RY gate on BOTH samples (independent chains interleaved).
template<int W>
DEVINL void apply_gate2(f32x2 (&aA)[16], f32x2 (&aB)[16], const float* cst, int lane) {
    constexpr GC gc = CC.g[10 + W];
    float tt = csw(cst[40 + W], sgnw(lane, gc.rowL));
    f32x2 tp; tp.x = tt;  tp.y = tt;
    f32x2 tn; tn.x = -tt; tn.y = -tt;
    if constexpr (gc.laneXor == 0) {
        #pragma unroll
        for (int r = 0; r < 16; ++r) {
            const int r2 = r ^ gc.regXor;
            if (r < r2) {
                const bool sR  = __builtin_popcount(unsigned(gc.rowR & r )) & 1;
                const bool sR2 = __builtin_popcount(unsigned(gc.rowR & r2)) & 1;
                { f32x2 ca = aA[r], cb = aA[r2];
                  aA[r]  = ca + (sR  ? tp : tn) * cb;
                  aA[r2] = cb + (sR2 ? tp : tn) * ca; }
                { f32x2 ca = aB[r], cb = aB[r2];
                  aB[r]  = ca + (sR  ? tp : tn) * cb;
                  aB[r2] = cb + (sR2 ? tp : tn) * ca; }
            }
        }
    } else if constexpr (gc.regXor == 0) {
        // 2 chunks of 8 regs x 2 samples staged (32 fetches in flight)
        #pragma unroll
        for (int ch = 0; ch < 2; ++ch) {
            f32x2 bA[8], bB[8];
            #pragma unroll
            for (int i = 0; i < 8; ++i) {
                const int r = ch * 8 + i;
                bA[i].x = fetch<gc.laneXor>(aA[r].x, lane);
                bA[i].y = fetch<gc.laneXor>(aA[r].y, lane);
                bB[i].x = fetch<gc.laneXor>(aB[r].x, lane);
                bB[i].y = fetch<gc.laneXor>(aB[r].y, lane);
            }
            #pragma unroll
            for (int i = 0; i < 8; ++i) {
                const int r = ch * 8 + i;
                const bool sR = __builtin_popcount(unsigned(gc.rowR & r)) & 1;
                pk_fma_acc(aA[r], sR ? tp : tn, bA[i]);
                pk_fma_acc(aB[r], sR ? tp : tn, bB[i]);
            }
        }
    } else {
        // paired lane gate; single-bit regXor -> closed-form static indices
        static_assert((gc.regXor & (gc.regXor - 1)) == 0, "regXor pow2");
        constexpr int bp = (gc.regXor == 8) ? 3 :
                           (gc.regXor == 4) ? 2 :
                           (gc.regXor == 2) ? 1 : 0;
        #pragma unroll
        for (int ch = 0; ch < 2; ++ch) {
            f32x2 loA[4], hiA[4], loB[4], hiB[4];
            #pragma unroll
            for (int i = 0; i < 4; ++i) {
                const int p  = ch * 4 + i;
                const int lo = ((p >> bp) << (bp + 1)) | (p & (gc.regXor - 1));
                const int hi = lo | gc.regXor;
                loA[i].x = fetch<gc.laneXor>(aA[hi].x, lane);
                loA[i].y = fetch<gc.laneXor>(aA[hi].y, lane);
                hiA[i].x = fetch<gc.laneXor>(aA[lo].x, lane);
                hiA[i].y = fetch<gc.laneXor>(aA[lo].y, lane);
                loB[i].x = fetch<gc.laneXor>(aB[hi].x, lane);
                loB[i].y = fetch<gc.laneXor>(aB[hi].y, lane);
                hiB[i].x = fetch<gc.laneXor>(aB[lo].x, lane);
                hiB[i].y = fetch<gc.laneXor>(aB[lo].y, lane);
            }
            #pragma unroll
            for (int i = 0; i < 4; ++i) {
                const int p  = ch * 4 + i;
                const int lo = ((p >> bp) << (bp + 1)) | (p & (gc.regXor - 1));
                const int hi = lo | gc.regXor;
                const bool sLo = __builtin_popcount(unsigned(gc.rowR & lo)) & 1;
                const bool sHi = __builtin_popcount(unsigned(gc.rowR & hi)) & 1;
                pk_fma_acc(aA[lo], sLo ? tp : tn, loA[i]);
                pk_fma_acc(aA[hi], sHi ? tp : tn, hiA[i]);
                pk_fma_acc(aB[lo], sLo ? tp : tn, loB[i]);
                pk_fma_acc(aB[hi], sHi ? tp : tn, hiB[i]);
            }
        }
    }
}

// probabilities + 4-bit reg WHT (stage 8 pruned) -> 10 signed expval terms
DEVINL void expvals(const f32x2 (&a2)[16], int lane, float (&e)[10]) {
    float wv[16];
    #pragma unroll
    for (int r = 0; r < 16; ++r) wv[r] = a2[r].x * a2[r].x + a2[r].y * a2[r].y;
    #pragma unroll
    for (int bS = 1; bS < 8; bS <<= 1) {
        #pragma unroll
        for (int r = 0; r < 16; ++r) {
            if (!(r & bS)) {
                float xv = wv[r], yv = wv[r | bS];
                wv[r]      = xv + yv;
                wv[r | bS] = xv - yv;
            }
        }
    }
    #pragma unroll
    for (int q = 0; q < 10; ++q) {
        const int R = CC.sgnR[q];
        float num = (R & 8) ? (wv[R ^ 8] - wv[R]) : (wv[R] + wv[R ^ 8]);
        int slq = __popc(unsigned(lane & CC.sgnL[q])) & 1;
        e[q] = csw(num, slq << 31);
    }
}

__global__ __launch_bounds__(256) void qsim(const float* __restrict__ x,
                                            float* __restrict__ out, int B) {
    const float* cst = g_cst;
    int lane = threadIdx.x & 63;
    int wid = threadIdx.x >> 6;
    int bA = blockIdx.x * 8 + wid * 2;      // 2 samples per wave (per thread)
    if (bA >= B) return;
    int bB = bA + 1;
    int bBl = (bB < B) ? bB : bA;           // safe load index

    const f32x2* xpA = reinterpret_cast<const f32x2*>(x + bA * 10);
    const f32x2* xpB = reinterpret_cast<const f32x2*>(x + bBl * 10);
    f32x2 a0 = xpA[0], a1 = xpA[1], a2v = xpA[2], a3 = xpA[3], a4 = xpA[4];
    f32x2 b0 = xpB[0], b1 = xpB[1], b2v = xpB[2], b3 = xpB[3], b4 = xpB[4];
    float xA[10] = { a0.x, a0.y, a1.x, a1.y, a2v.x, a2v.y, a3.x, a3.y, a4.x, a4.y };
    float xB[10] = { b0.x, b0.y, b1.x, b1.y, b2v.x, b2v.y, b3.x, b3.y, b4.x, b4.y };

    f32x2 sA[16], sB[16];
    build_state(cst, xA, lane, sA);
    build_state(cst, xB, lane, sB);

    // gates (commuting); bperm first, swz mid, DPP/local fill
    apply_gate2<5>(sA, sB, cst, lane);   // bperm32 (reg^8)
    apply_gate2<6>(sA, sB, cst, lane);   // local reg^12
    apply_gate2<4>(sA, sB, cst, lane);   // swz16
    apply_gate2<7>(sA, sB, cst, lane);   // local reg^6
    apply_gate2<3>(sA, sB, cst, lane);   // DPP xor7 (half_mirror)
    apply_gate2<8>(sA, sB, cst, lane);   // local reg^3
    apply_gate2<2>(sA, sB, cst, lane);   // DPP xor8 (ror8)
    apply_gate2<1>(sA, sB, cst, lane);   // DPP xor2
    apply_gate2<0>(sA, sB, cst, lane);   // DPP xor1
    apply_gate2<9>(sA, sB, cst, lane);   // DPP xor1 (reg^1)

    float eA[10], eB[10];
    expvals(sA, lane, eA);
    expvals(sB, lane, eB);

    // lane reduction over 64 lanes, both samples interleaved:
    // quad (DPP 1,2), slot-pack 10->3, then xor4(swz)/xor8(DPP)/16/32(permlane sums)
    #pragma unroll
    for (int q = 0; q < 10; ++q) {
        eA[q] += fetch<1>(eA[q], lane);
        eB[q] += fetch<1>(eB[q], lane);
        eA[q] += fetch<2>(eA[q], lane);
        eB[q] += fetch<2>(eB[q], lane);
    }
    int s = lane & 3;
    bool s1 = (s & 1) != 0, s2 = (s & 2) != 0;
    float vA0 = s1 ? eA[1] : eA[0];
    float uA0 = s1 ? eA[3] : eA[2];
    vA0 = s2 ? uA0 : vA0;
    float vA1 = s1 ? eA[5] : eA[4];
    float uA1 = s1 ? eA[7] : eA[6];
    vA1 = s2 ? uA1 : vA1;
    float vA2 = s1 ? eA[9] : eA[8];
    float vB0 = s1 ? eB[1] : eB[0];
    float uB0 = s1 ? eB[3] : eB[2];
    vB0 = s2 ? uB0 : vB0;
    float vB1 = s1 ? eB[5] : eB[4];
    float uB1 = s1 ? eB[7] : eB[6];
    vB1 = s2 ? uB1 : vB1;
    float vB2 = s1 ? eB[9] : eB[8];

    vA0 += fetch<4>(vA0, lane);  vA1 += fetch<4>(vA1, lane);  vA2 += fetch<4>(vA2, lane);
    vB0 += fetch<4>(vB0, lane);  vB1 += fetch<4>(vB1, lane);  vB2 += fetch<4>(vB2, lane);
    vA0 += fetch<8>(vA0, lane);  vA1 += fetch<8>(vA1, lane);  vA2 += fetch<8>(vA2, lane);
    vB0 += fetch<8>(vB0, lane);  vB1 += fetch<8>(vB1, lane);  vB2 += fetch<8>(vB2, lane);
    vA0 = bsum16(vA0, lane);     vA1 = bsum16(vA1, lane);     vA2 = bsum16(vA2, lane);
    vB0 = bsum16(vB0, lane);     vB1 = bsum16(vB1, lane);     vB2 = bsum16(vB2, lane);
    vA0 = bsum32(vA0, lane);     vA1 = bsum32(vA1, lane);     vA2 = bsum32(vA2, lane);
    vB0 = bsum32(vB0, lane);     vB1 = bsum32(vB1, lane);     vB2 = bsum32(vB2, lane);

    // lane q holds full sum of e[q] in v_{q>>2} (slot matches lane&3)
    float voA = vA0, voB = vB0;
    int hi = lane >> 2;
    voA = (hi == 1) ? vA1 : voA;  voA = (hi == 2) ? vA2 : voA;
    voB = (hi == 1) ? vB1 : voB;  voB = (hi == 2) ? vB2 : voB;
    if (lane < 10) {
        out[bA * 10 + lane] = voA;
        if (bB < B) out[bB * 10 + lane] = voB;
    }
}

extern "C" void kernel_launch(void* const* d_in, const int* in_sizes, int n_in,
                              void* d_out, int out_size, void* d_ws, size_t ws_size,
                              hipStream_t stream) {
    const float* x  = (const float*)d_in[0];
    const float* qw = (const float*)d_in[1];
    float* out = (float*)d_out;
    int B = in_sizes[0] / 10;
    int blocks = (B + 7) / 8;   // 8 samples per 256-thread block (2 per wave)
    hipLaunchKernelGGL(qprep, dim3(1), dim3(64), 0, stream, qw);
    hipLaunchKernelGGL(qsim, dim3(blocks), dim3(256), 0, stream, x, out, B);
}

// Round 16
// 80.324 us; speedup vs baseline: 1.0714x; 1.0714x over previous
//
#include <hip/hip_runtime.h>

#define DEVINL __device__ __forceinline__

typedef float f32x2 __attribute__((ext_vector_type(2)));

// ---------------------------------------------------------------------------
// Compile-time circuit constants via GF(2) linear-map tracking.
// Physical index q (10 bits): bits 9..5 = lane l5 (5 bits), bits 4..0 = reg.
// Lane bit 5 of the hw lane = SAMPLE SELECT (2 samples per wave).
//
// Round-16 == Round-14 resubmitted again (R14, R15 were both broker/container
// infra failures; same error string as R4 which later ran clean as R5).
// R14 = R10 (best known: 81.9us bench, qsim ~38-40) + algebraic gate-folding
// (R13's explicit 2-sample ILP regressed: doubled code+regs):
//  * w5 (reg^24 -> j^6, sign bit2(j)) and w6 (reg^12 -> j^3, sign par(j&6))
//    act purely on the j-factor -> folded into the 8-entry tf table
//    (8 pk_fma each instead of 32 on the full state).  Valid because
//    parity(j^6)=parity(j) and parity(j^3)=parity(j), so the v-factor
//    g4H[v][sel(v,par(j))] is identical for both pair members.
//  * w8 (reg^3 -> v^3): sel flips with v>>1, sign = par(v&2)^par(j) ->
//    folded into g4Hp[v][P=par(j)] (8 pk_fma instead of 32).
//  * Remaining full gates: w4(swz16,reg^16), w7(local reg^6), w3(DPP ror8),
//    w1(swz12), w2(DPP2), w0(DPP1), w9(DPP1,reg^1).
//  * Everything else identical to R10: no launch-bounds clamp, signs
//    recomputed per use, cumulative E-products, SSA local gates.
// ---------------------------------------------------------------------------
struct GC { int laneXor, regXor, rowL, rowR; };
struct Circ { GC g[20]; int sgnL[10], sgnR[10]; int lsel[5]; };

constexpr Circ build_circ() {
    Circ c{};
    unsigned A[10] = {};
    for (int i = 0; i < 10; ++i) A[i] = 1u << i;
    for (int w = 0; w < 10; ++w) {
        int pos = 9 - w;
        unsigned m = 1u << pos;
        c.g[w] = GC{ int(m >> 5), int(m & 31u), int(m >> 5), int(m & 31u) };
    }
    // layer 0 CNOT ring, range r=1
    for (int q = 0; q < 10; ++q) { int pc = 9 - q, pt = 9 - ((q + 1) % 10); A[pt] ^= A[pc]; }
    // invert A over GF(2)
    unsigned M[10] = {}, Inv[10] = {};
    for (int i = 0; i < 10; ++i) { M[i] = A[i]; Inv[i] = 1u << i; }
    for (int col = 0; col < 10; ++col) {
        int piv = col;
        while (!((M[piv] >> col) & 1u)) ++piv;
        unsigned tm = M[col]; M[col] = M[piv]; M[piv] = tm;
        unsigned ti = Inv[col]; Inv[col] = Inv[piv]; Inv[piv] = ti;
        for (int r = 0; r < 10; ++r)
            if (r != col && ((M[r] >> col) & 1u)) { M[r] ^= M[col]; Inv[r] ^= Inv[col]; }
    }
    // layer 1 Rot gates in p-space (5/5 split): m = A^{-1} e_pos, row = A[pos]
    for (int w = 0; w < 10; ++w) {
        int pos = 9 - w;
        unsigned m = 0;
        for (int i = 0; i < 10; ++i) m |= ((Inv[i] >> pos) & 1u) << i;
        unsigned row = A[pos];
        c.g[10 + w] = GC{ int(m >> 5), int(m & 31u), int(row >> 5), int(row & 31u) };
    }
    // layer 1 CNOT ring, range r=2
    for (int q = 0; q < 10; ++q) { int pc = 9 - q, pt = 9 - ((q + 2) % 10); A[pt] ^= A[pc]; }
    for (int q = 0; q < 10; ++q) { unsigned row = A[9 - q]; c.sgnL[q] = int(row >> 5); c.sgnR[q] = int(row & 31u); }

    // ---- basis change on the 5 lane bits -------------------------------
    // u1={b0}(w4), u2={b0,b1}(w3), u3={b1,b2}(w2), u4={b2,b3}(w1),
    // u5={b3,b4}(w0 AND w9, doubled).  Map u1..u5 -> {16, 8, 2, 12, 1}.
    unsigned Ucols[5] = {};
    {
        unsigned tgt[5] = {16, 8, 2, 12, 1};
        unsigned acc = 0;
        for (int k = 0; k < 5; ++k) { acc ^= tgt[k]; Ucols[k] = acc; }
    }
    unsigned Urows[5] = {};
    for (int r = 0; r < 5; ++r)
        for (int cc = 0; cc < 5; ++cc)
            Urows[r] |= ((Ucols[cc] >> r) & 1u) << cc;
    unsigned MM[5] = {}, AI[5] = {};
    for (int i = 0; i < 5; ++i) { MM[i] = Urows[i]; AI[i] = 1u << i; }
    for (int col = 0; col < 5; ++col) {
        int piv = col;
        while (!((MM[piv] >> col) & 1u)) ++piv;
        unsigned tm = MM[col]; MM[col] = MM[piv]; MM[piv] = tm;
        unsigned ti = AI[col]; AI[col] = AI[piv]; AI[piv] = ti;
        for (int r = 0; r < 5; ++r)
            if (r != col && ((MM[r] >> col) & 1u)) { MM[r] ^= MM[col]; AI[r] ^= AI[col]; }
    }
    for (int w = 0; w < 10; ++w) {
        unsigned mL = unsigned(c.g[10 + w].laneXor);
        unsigned nm = 0;
        for (int i = 0; i < 5; ++i) if ((mL >> i) & 1u) nm ^= Ucols[i];
        c.g[10 + w].laneXor = int(nm);
        unsigned rL = unsigned(c.g[10 + w].rowL);
        unsigned nr = 0;
        for (int i = 0; i < 5; ++i) if ((rL >> i) & 1u) nr ^= AI[i];
        c.g[10 + w].rowL = int(nr);
    }
    for (int q = 0; q < 10; ++q) {
        unsigned sL = unsigned(c.sgnL[q]);
        unsigned ns = 0;
        for (int i = 0; i < 5; ++i) if ((sL >> i) & 1u) ns ^= AI[i];
        c.sgnL[q] = int(ns);
    }
    for (int o = 0; o < 5; ++o) c.lsel[o] = int(AI[o]);
    return c;
}

constexpr Circ CC = build_circ();

// Final gate inventory this schedule depends on (computed, then asserted).
static_assert(CC.g[10].laneXor == 1  && CC.g[10].regXor == 0,  "w0");
static_assert(CC.g[11].laneXor == 12 && CC.g[11].regXor == 0,  "w1");
static_assert(CC.g[12].laneXor == 2  && CC.g[12].regXor == 0,  "w2");
static_assert(CC.g[13].laneXor == 8  && CC.g[13].regXor == 0,  "w3");
static_assert(CC.g[14].laneXor == 16 && CC.g[14].regXor == 16, "w4");
static_assert(CC.g[15].laneXor == 0  && CC.g[15].regXor == 24, "w5");
static_assert(CC.g[16].laneXor == 0  && CC.g[16].regXor == 12, "w6");
static_assert(CC.g[17].laneXor == 0  && CC.g[17].regXor == 6,  "w7");
static_assert(CC.g[18].laneXor == 0  && CC.g[18].regXor == 3,  "w8");
static_assert(CC.g[19].laneXor == 1  && CC.g[19].regXor == 1,  "w9");
static_assert(CC.g[10].rowR == 31, "w0 rowR");
static_assert(CC.g[11].rowR == 0,  "w1 rowR");
static_assert(CC.g[12].rowR == 0,  "w2 rowR");
static_assert(CC.g[13].rowR == 0,  "w3 rowR");
static_assert(CC.g[14].rowR == 0,  "w4 rowR");
static_assert(CC.g[15].rowR == 16, "w5 rowR");   // fold: sign = bit2(j)
static_assert(CC.g[16].rowR == 24, "w6 rowR");   // fold: sign = par(j&6)
static_assert(CC.g[17].rowR == 28, "w7 rowR");
static_assert(CC.g[18].rowR == 30, "w8 rowR");   // fold: sign = par(v&2)^par(j)
static_assert(CC.g[19].rowR == 31, "w9 rowR");

// sign-word xor: sw has the sign in bit 31 (or is 0)
DEVINL float csw(float v, int sw) {
    return __int_as_float(__float_as_int(v) ^ sw);
}
// lane-parity sign word for a rowL mask (recomputed per use; frees regs)
DEVINL int sgnw(int l5, int rowL) {
    return (__popc(unsigned(l5 & rowL)) & 1) << 31;
}

// lane-xor fetch:
//   1,2,3 -> DPP quad_perm; 8 -> DPP row_ror:8 (proven R7/R8/R12);
//   else (<32) -> ds_swizzle.  All patterns stay within 32-lane halves.
template<int XOR>
DEVINL float fetch(float v) {
    if constexpr (XOR == 0)      return v;
    else if constexpr (XOR == 1) return __int_as_float(__builtin_amdgcn_update_dpp(0, __float_as_int(v), 0xB1, 0xF, 0xF, true));
    else if constexpr (XOR == 2) return __int_as_float(__builtin_amdgcn_update_dpp(0, __float_as_int(v), 0x4E, 0xF, 0xF, true));
    else if constexpr (XOR == 3) return __int_as_float(__builtin_amdgcn_update_dpp(0, __float_as_int(v), 0x1B, 0xF, 0xF, true));
    else if constexpr (XOR == 8) return __int_as_float(__builtin_amdgcn_update_dpp(0, __float_as_int(v), 0x128, 0xF, 0xF, true));
    else                         return __int_as_float(__builtin_amdgcn_ds_swizzle(__float_as_int(v), 0x1F | (XOR << 10)));
}

// forced packed FMA for in-place accumulate against a TEMP operand
DEVINL void pk_fma_acc(f32x2& a, f32x2 t, f32x2 b) {
    asm("v_pk_fma_f32 %0, %1, %2, %0" : "+v"(a) : "v"(t), "v"(b));
}

DEVINL f32x2 cmul(f32x2 a, f32x2 b) {
    f32x2 r;
    r.x = a.x * b.x - a.y * b.y;
    r.y = a.x * b.y + a.y * b.x;
    return r;
}

// ---------------------------------------------------------------------------
// Constants, computed once by qprep (wire-indexed; basis-agnostic):
// [0..39]  layer-0 Rot mats (u00r,u00i,u01r,u01i per wire)
// [40..49] layer-1 tan(th/2) per wire
// [50..69] layer-1 (cos(phi/2), -sin(phi/2)) per wire
// [70]     prod_w cos(th_w/2)
// ---------------------------------------------------------------------------
__device__ __attribute__((aligned(16))) float g_cst[80];

__global__ void qprep(const float* __restrict__ qw) {
    int g = threadIdx.x;
    if (g < 10) {
        float phi = qw[g * 3 + 0], th = qw[g * 3 + 1], om = qw[g * 3 + 2];
        float c = cosf(0.5f * th), s = sinf(0.5f * th);
        float apo = 0.5f * (phi + om), amo = 0.5f * (phi - om);
        g_cst[g * 4 + 0] =  cosf(apo) * c;
        g_cst[g * 4 + 1] = -sinf(apo) * c;
        g_cst[g * 4 + 2] = -cosf(amo) * s;
        g_cst[g * 4 + 3] = -sinf(amo) * s;
    } else if (g < 20) {
        int w = g - 10;
        float phi = qw[g * 3 + 0], th = qw[g * 3 + 1];
        float c = cosf(0.5f * th), s = sinf(0.5f * th);
        g_cst[40 + w] = s / c;
        g_cst[50 + w * 2 + 0] =  cosf(0.5f * phi);
        g_cst[50 + w * 2 + 1] = -sinf(0.5f * phi);
    } else if (g == 20) {
        float p = 1.f;
        for (int w = 0; w < 10; ++w) p *= cosf(0.5f * qw[(10 + w) * 3 + 1]);
        g_cst[70] = p;
    }
}

// lane-signed RZ(phi) phase constant E_w = (cos, +-sin), sign from gate rowL
DEVINL f32x2 mkE(const float* cst, int w, int l5) {
    f32x2 E;
    E.x = cst[50 + w * 2];
    E.y = csw(cst[50 + w * 2 + 1], sgnw(l5, CC.g[10 + w].rowL));
    return E;
}

// per-wire embedding factor: |0> --RY(x)--> --Rot(layer0)--> (f0, f1)
DEVINL void wf(const float* cst, float xw, int w, f32x2& f0, f32x2& f1) {
    float h = 0.5f * xw;
    float s = __sinf(h), c = __cosf(h);
    float m0 = cst[w * 4 + 0], m1 = cst[w * 4 + 1], m2 = cst[w * 4 + 2], m3 = cst[w * 4 + 3];
    f0.x =  m0 * c + m2 * s;
    f0.y =  m1 * c + m3 * s;
    f1.x = -m2 * c + m0 * s;
    f1.y =  m3 * c - m1 * s;
}

// Layer-1 RY gate as fast-Givens on packed {re,im}: a' = a +- t*b.
template<int W>
DEVINL void apply_gate(f32x2 (&a2)[32], const float* cst, int l5) {
    constexpr GC gc = CC.g[10 + W];
    float tt = csw(cst[40 + W], sgnw(l5, gc.rowL));
    f32x2 tp; tp.x = tt;  tp.y = tt;
    f32x2 tn; tn.x = -tt; tn.y = -tt;
    if constexpr (gc.laneXor == 0) {
        #pragma unroll
        for (int r = 0; r < 32; ++r) {
            const int r2 = r ^ gc.regXor;
            if (r < r2) {
                const bool sR  = __builtin_popcount(unsigned(gc.rowR & r )) & 1;
                const bool sR2 = __builtin_popcount(unsigned(gc.rowR & r2)) & 1;
                f32x2 ca = a2[r], cb = a2[r2];
                f32x2 na = ca + (sR  ? tp : tn) * cb;   // -> v_pk_fma, SSA
                f32x2 nb = cb + (sR2 ? tp : tn) * ca;
                a2[r] = na; a2[r2] = nb;
            }
        }
    } else if constexpr (gc.regXor == 0) {
        #pragma unroll
        for (int r = 0; r < 32; ++r) {
            f32x2 b;
            b.x = fetch<gc.laneXor>(a2[r].x);
            b.y = fetch<gc.laneXor>(a2[r].y);
            const bool sR = __builtin_popcount(unsigned(gc.rowR & r)) & 1;
            pk_fma_acc(a2[r], sR ? tp : tn, b);
        }
    } else {
        #pragma unroll
        for (int r = 0; r < 32; ++r) {
            const int r2 = r ^ gc.regXor;
            if (r < r2) {
                f32x2 blo, bhi;
                blo.x = fetch<gc.laneXor>(a2[r2].x);
                blo.y = fetch<gc.laneXor>(a2[r2].y);
                bhi.x = fetch<gc.laneXor>(a2[r].x);
                bhi.y = fetch<gc.laneXor>(a2[r].y);
                const bool sR  = __builtin_popcount(unsigned(gc.rowR & r )) & 1;
                const bool sR2 = __builtin_popcount(unsigned(gc.rowR & r2)) & 1;
                pk_fma_acc(a2[r],  sR  ? tp : tn, blo);
                pk_fma_acc(a2[r2], sR2 ? tp : tn, bhi);
            }
        }
    }
}

__global__ __launch_bounds__(256) void qsim(const float* __restrict__ x,
                                            float* __restrict__ out, int B) {
    const float* cst = g_cst;
    int lane = threadIdx.x & 63;
    int l5 = lane & 31;                        // 5-bit lane within the sample
    int b = blockIdx.x * 8 + (threadIdx.x >> 5);   // 2 samples/wave, 8/block
    if (b >= B) return;

    // ---- vectorized x load: 5x dwordx2 (b*40 bytes ≡ 0 mod 8)
    const f32x2* xp = reinterpret_cast<const f32x2*>(x + b * 10);
    f32x2 xv0 = xp[0], xv1 = xp[1], xv2 = xp[2], xv3 = xp[3], xv4 = xp[4];
    float xw[10] = { xv0.x, xv0.y, xv1.x, xv1.y, xv2.x,
                     xv2.y, xv3.x, xv3.y, xv4.x, xv4.y };

    // ---- reg-wire tables: bit0=w9, bit1=w8, bit2=w7, bit3=w6, bit4=w5
    f32x2 t01[4], t23[4], f5t[2];
    {
        f32x2 a0, a1, b0, b1;
        wf(cst, xw[9], 9, a0, a1);
        wf(cst, xw[8], 8, b0, b1);
        t01[0] = cmul(a0, b0); t01[1] = cmul(a1, b0);
        t01[2] = cmul(a0, b1); t01[3] = cmul(a1, b1);
        wf(cst, xw[7], 7, a0, a1);
        wf(cst, xw[6], 6, b0, b1);
        t23[0] = cmul(a0, b0); t23[1] = cmul(a1, b0);
        t23[2] = cmul(a0, b1); t23[3] = cmul(a1, b1);
        wf(cst, xw[5], 5, f5t[0], f5t[1]);
    }

    // ---- lane factor: selected wire factors (tree) * E_A(w1..w4) * cos-prod
    f32x2 lf;
    {
        f32x2 p0, p1, p2, p3, p4;
        {
            f32x2 f0, f1;
            wf(cst, xw[4], 4, f0, f1);
            int bit = __popc(unsigned(l5 & CC.lsel[0])) & 1;
            p0.x = bit ? f1.x : f0.x;  p0.y = bit ? f1.y : f0.y;
            wf(cst, xw[3], 3, f0, f1);
            bit = __popc(unsigned(l5 & CC.lsel[1])) & 1;
            p1.x = bit ? f1.x : f0.x;  p1.y = bit ? f1.y : f0.y;
            wf(cst, xw[2], 2, f0, f1);
            bit = __popc(unsigned(l5 & CC.lsel[2])) & 1;
            p2.x = bit ? f1.x : f0.x;  p2.y = bit ? f1.y : f0.y;
            wf(cst, xw[1], 1, f0, f1);
            bit = __popc(unsigned(l5 & CC.lsel[3])) & 1;
            p3.x = bit ? f1.x : f0.x;  p3.y = bit ? f1.y : f0.y;
            wf(cst, xw[0], 0, f0, f1);
            bit = __popc(unsigned(l5 & CC.lsel[4])) & 1;
            p4.x = bit ? f1.x : f0.x;  p4.y = bit ? f1.y : f0.y;
        }
        f32x2 pl = cmul(cmul(cmul(p0, p1), cmul(p2, p3)), p4);
        f32x2 ea = mkE(cst, 1, l5);
        ea = cmul(ea, mkE(cst, 2, l5));
        ea = cmul(ea, mkE(cst, 3, l5));
        ea = cmul(ea, mkE(cst, 4, l5));
        float sc = cst[70];
        ea.x *= sc; ea.y *= sc;
        lf = cmul(pl, ea);
    }

    // ---- fold w5 phase into f5 (bit4); V (w6,w7) and H (w8,w9,w0) products
    f32x2 f5p[2], V00, V01, H0, H1;
    {
        f32x2 E5 = mkE(cst, 5, l5);
        f5p[0] = cmul(f5t[0], E5);
        E5.y = -E5.y;
        f5p[1] = cmul(f5t[1], E5);
        f32x2 E6 = mkE(cst, 6, l5), E7 = mkE(cst, 7, l5);
        V00 = cmul(E6, E7);
        E7.y = -E7.y;
        V01 = cmul(E6, E7);
        f32x2 EB = cmul(mkE(cst, 9, l5), mkE(cst, 0, l5));
        f32x2 E8 = mkE(cst, 8, l5);
        H0 = cmul(E8, EB);
        EB.y = -EB.y;
        H1 = cmul(E8, EB);
    }

    // ---- g4H[v][sel]: lf * t01[v] * (H(v&1) or conj)
    f32x2 g4H[4][2];
    #pragma unroll
    for (int v = 0; v < 4; ++v) {
        f32x2 g = cmul(lf, t01[v]);
        f32x2 H = (v & 1) ? H1 : H0;
        g4H[v][0] = cmul(g, H);
        f32x2 Hc; Hc.x = H.x; Hc.y = -H.y;
        g4H[v][1] = cmul(g, Hc);
    }

    // ---- tf[8] table (j = reg bits 2,3,4)
    f32x2 tf[8];
    #pragma unroll
    for (int j = 0; j < 8; ++j) {
        f32x2 tA = cmul(t23[j & 3], f5p[j >> 2]);
        const int s6 = ((j >> 2) ^ (j >> 1)) & 1;
        const int s7 = s6 ^ (j & 1);
        f32x2 V;
        V.x = s6 ? (s7 ? V00.x : V01.x) : (s7 ? V01.x : V00.x);
        V.y = s6 ? -(s7 ? V00.y : V01.y) : (s7 ? V01.y : V00.y);
        tf[j] = cmul(tA, V);
    }

    // ---- FOLD gate w5 into tf:  j <-> j^6, sign = bit2(j) (rowR=16)
    {
        float t5 = csw(cst[40 + 5], sgnw(l5, CC.g[15].rowL));
        f32x2 tp; tp.x = t5;  tp.y = t5;
        f32x2 tn; tn.x = -t5; tn.y = -t5;
        #pragma unroll
        for (int j = 0; j < 8; ++j) {
            const int j2 = j ^ 6;
            if (j < j2) {
                f32x2 ca = tf[j], cb = tf[j2];
                tf[j]  = ca + (((j  >> 2) & 1) ? tp : tn) * cb;
                tf[j2] = cb + (((j2 >> 2) & 1) ? tp : tn) * ca;
            }
        }
    }
    // ---- FOLD gate w6 into tf:  j <-> j^3, sign = par(j&6) (rowR=24)
    {
        float t6 = csw(cst[40 + 6], sgnw(l5, CC.g[16].rowL));
        f32x2 tp; tp.x = t6;  tp.y = t6;
        f32x2 tn; tn.x = -t6; tn.y = -t6;
        #pragma unroll
        for (int j = 0; j < 8; ++j) {
            const int j2 = j ^ 3;
            if (j < j2) {
                const bool sA = (((j  >> 1) ^ (j  >> 2)) & 1);
                const bool sB = (((j2 >> 1) ^ (j2 >> 2)) & 1);
                f32x2 ca = tf[j], cb = tf[j2];
                tf[j]  = ca + (sA ? tp : tn) * cb;
                tf[j2] = cb + (sB ? tp : tn) * ca;
            }
        }
    }
    // ---- FOLD gate w8 into g4H -> g4Hp[v][P]:
    //      v <-> v^3, sel flips, sign = par(v&2)^P (rowR=30)
    f32x2 g4Hp[4][2];
    {
        float t8 = csw(cst[40 + 8], sgnw(l5, CC.g[18].rowL));
        f32x2 tp; tp.x = t8;  tp.y = t8;
        f32x2 tn; tn.x = -t8; tn.y = -t8;
        #pragma unroll
        for (int v = 0; v < 4; ++v) {
            #pragma unroll
            for (int P = 0; P < 2; ++P) {
                const int sel = ((v >> 1) ^ P) & 1;
                const bool sg = ((((v >> 1) & 1) ^ P) & 1);
                g4Hp[v][P] = g4H[v][sel] + (sg ? tp : tn) * g4H[v ^ 3][sel ^ 1];
            }
        }
    }

    // ---- amps: a2[(j<<2)|v] = g4Hp[v][par(j)] * tf[j]
    f32x2 a2[32];
    #pragma unroll
    for (int j = 0; j < 8; ++j) {
        const int pj = (j ^ (j >> 1) ^ (j >> 2)) & 1;
        #pragma unroll
        for (int v = 0; v < 4; ++v) {
            a2[(j << 2) | v] = cmul(g4Hp[v][pj], tf[j]);
        }
    }

    // ---- remaining layer-1 RY gates (w5,w6,w8 pre-folded; all commute)
    apply_gate<4>(a2, cst, l5);   // swz16 (reg^16)
    apply_gate<7>(a2, cst, l5);   // local reg^6
    apply_gate<3>(a2, cst, l5);   // DPP xor8 (row_ror:8)
    apply_gate<1>(a2, cst, l5);   // swz12
    apply_gate<2>(a2, cst, l5);   // DPP xor2
    apply_gate<0>(a2, cst, l5);   // DPP xor1
    apply_gate<9>(a2, cst, l5);   // DPP xor1 (reg^1)

    // ---- probabilities + reg-WHT stages 1,2,4,8 (stage 16 pruned into e[q])
    float wv[32];
    #pragma unroll
    for (int r = 0; r < 32; ++r) wv[r] = a2[r].x * a2[r].x + a2[r].y * a2[r].y;
    #pragma unroll
    for (int bS = 1; bS < 16; bS <<= 1) {
        #pragma unroll
        for (int r = 0; r < 32; ++r) {
            if (!(r & bS)) {
                float xvv = wv[r], yv = wv[r | bS];
                wv[r]      = xvv + yv;
                wv[r | bS] = xvv - yv;
            }
        }
    }

    float e[10];
    #pragma unroll
    for (int q = 0; q < 10; ++q) {
        const int R = CC.sgnR[q];
        float num = (R & 16) ? (wv[R ^ 16] - wv[R]) : (wv[R] + wv[R ^ 16]);
        int slq = __popc(unsigned(l5 & CC.sgnL[q])) & 1;
        e[q] = csw(num, slq << 31);
    }

    // ---- lane reduction within each 32-half: DPP quad-reduce, slot-pack to
    //      3, then xor4 (swz) / xor8 (DPP ror8) / xor16 (swz)
    #pragma unroll
    for (int q = 0; q < 10; ++q) {
        e[q] += fetch<1>(e[q]);
        e[q] += fetch<2>(e[q]);
    }
    int s = l5 & 3;
    bool s1 = (s & 1) != 0, s2 = (s & 2) != 0;
    float v0 = s1 ? e[1] : e[0];
    float u0 = s1 ? e[3] : e[2];
    v0 = s2 ? u0 : v0;
    float v1 = s1 ? e[5] : e[4];
    float u1 = s1 ? e[7] : e[6];
    v1 = s2 ? u1 : v1;
    float v2 = s1 ? e[9] : e[8];

    v0 += fetch<4>(v0);   v1 += fetch<4>(v1);   v2 += fetch<4>(v2);
    v0 += fetch<8>(v0);   v1 += fetch<8>(v1);   v2 += fetch<8>(v2);
    v0 += fetch<16>(v0);  v1 += fetch<16>(v1);  v2 += fetch<16>(v2);

    // lane l5==q holds full sum of e[q] in v_{q>>2} (slot matches l5&3)
    float vo = v0;
    int hi = l5 >> 2;
    vo = (hi == 1) ? v1 : vo;
    vo = (hi == 2) ? v2 : vo;
    if (l5 < 10) out[b * 10 + l5] = vo;
}

extern "C" void kernel_launch(void* const* d_in, const int* in_sizes, int n_in,
                              void* d_out, int out_size, void* d_ws, size_t ws_size,
                              hipStream_t stream) {
    const float* x  = (const float*)d_in[0];
    const float* qw = (const float*)d_in[1];
    float* out = (float*)d_out;
    int B = in_sizes[0] / 10;
    int blocks = (B + 7) / 8;   // 8 samples per 256-thread block (2 per wave)
    hipLaunchKernelGGL(qprep, dim3(1), dim3(64), 0, stream, qw);
    hipLaunchKernelGGL(qsim, dim3(blocks), dim3(256), 0, stream, x, out, B);
}